// Round 4
// baseline (1396.303 us; speedup 1.0000x reference)
//
#include <hip/hip_runtime.h>
#include <math.h>

#define NN 50000
#define NE 1000000
#define NG 256
#define ORIGD 92
#define NBRD 41
#define NSPREAD 32
#define SCAN_B 256

typedef unsigned short u16;
typedef __attribute__((ext_vector_type(8))) short short8;   // 8 x bf16 MFMA frag
typedef __attribute__((ext_vector_type(4))) float f32x4;    // MFMA accumulator

// ---- workspace layout (float offsets) ----
#define OFF_AFB     0                        // 50000*64 bf16
#define OFF_SUMMED  1600000                  // 50000*64 fp32
#define OFF_WT      4800000                  // 128*192 bf16
#define OFF_BN1SPR  4812288                  // 32*256
#define OFF_BN1SC   4820480                  // 256
#define OFF_BN2ACC  4820736                  // 128
#define OFF_BN2SC   4820864                  // 128
#define OFF_ELOG    4820992                  // 50000
#define OFF_SEGMAX  4870992                  // 256
#define OFF_DENOM   4871248                  // 256
#define OFF_CNT     4871504                  // 50000 int
#define OFF_PTR     4921504                  // 50000 int
#define OFF_HEAD    4971504                  // 50000 int
#define OFF_BSUM    5021504                  // 256 int
#define OFF_BOFS    5021760                  // 256 int
#define OFF_SLOT    5022016                  // 1M int (CSR position per edge)
#define OFF_H       6022016                  // 1M*128 bf16 (256 MB)
#define OFF_T2_END  70022016                 // tier2: h, no eab (~280 MB)
#define OFF_EAB     70022016                 // 1M*48 bf16 (96 MB)
#define OFF_T3_END  94022016                 // tier3 (~376 MB)

__device__ __forceinline__ u16 f2b(float f) {          // fp32 -> bf16 RNE
    unsigned u = __float_as_uint(f);
    return (u16)((u + 0x7FFFu + ((u >> 16) & 1u)) >> 16);
}
__device__ __forceinline__ float b2f(u16 u) {
    return __uint_as_float(((unsigned)u) << 16);
}

// ---------------- embed: afb = bf16(x@emb_W + emb_b + lower_f) ----------------
__global__ __launch_bounds__(256) void k_embed(
    const float* __restrict__ x, const float* __restrict__ lf,
    const float* __restrict__ W, const float* __restrict__ b,
    u16* __restrict__ afb)
{
    int gid = blockIdx.x * 256 + threadIdx.x;
    int n = gid >> 6, c = gid & 63;
    const float* xr = x + (long)n * ORIGD;
    float acc = b[c] + lf[gid];
#pragma unroll 4
    for (int k = 0; k < ORIGD; k++)
        acc = fmaf(xr[k], W[k * 64 + c], acc);
    afb[gid] = f2b(acc);
}

// ---------------- prep: wT[j][k] = bf16(fc_W[k][j]), K padded 169->192 ----------------
__global__ void k_prepw(const float* __restrict__ fcW, u16* __restrict__ wT)
{
    int i = blockIdx.x * 256 + threadIdx.x;        // 24576
    int j = i / 192, k = i - j * 192;
    wT[i] = (k < 169) ? f2b(fcW[k * 128 + j]) : (u16)0;
}

// ---------------- prep: eab = bf16(edge_attr), rows padded 41->48 ----------------
__global__ void k_prepea(const float* __restrict__ ea, u16* __restrict__ eab)
{
    int gid = blockIdx.x * 256 + threadIdx.x;      // 48M exactly
    int e = gid / 48, c = gid - e * 48;
    eab[gid] = (c < NBRD) ? f2b(ea[(long)e * NBRD + c]) : (u16)0;
}

// ---------------- CSR build ----------------
__global__ void k_hist(const int* __restrict__ ei, int* __restrict__ cnt)
{
    int e = blockIdx.x * 256 + threadIdx.x;
    if (e < NE) atomicAdd(&cnt[ei[e]], 1);
}

__global__ void k_partial(const int* __restrict__ cnt, int* __restrict__ lofs,
                          int* __restrict__ bsum)
{
    __shared__ int sd[SCAN_B];
    int t = threadIdx.x, b = blockIdx.x, n = b * SCAN_B + t;
    int v = (n < NN) ? cnt[n] : 0;
    sd[t] = v; __syncthreads();
    for (int o = 1; o < SCAN_B; o <<= 1) {
        int x = (t >= o) ? sd[t - o] : 0;
        __syncthreads();
        sd[t] += x;
        __syncthreads();
    }
    if (n < NN) lofs[n] = sd[t] - v;
    if (t == SCAN_B - 1) bsum[b] = sd[t];
}

__global__ void k_scanb(const int* __restrict__ bsum, int* __restrict__ bofs, int nb)
{
    __shared__ int sd[256];
    int t = threadIdx.x;
    int v = (t < nb) ? bsum[t] : 0;
    sd[t] = v; __syncthreads();
    for (int o = 1; o < 256; o <<= 1) {
        int x = (t >= o) ? sd[t - o] : 0;
        __syncthreads();
        sd[t] += x;
        __syncthreads();
    }
    bofs[t] = sd[t] - v;
}

__global__ void k_addofs(int* __restrict__ ptr, const int* __restrict__ bofs,
                         int* __restrict__ head)
{
    int n = blockIdx.x * 256 + threadIdx.x;
    if (n < NN) {
        int p = ptr[n] + bofs[n >> 8];
        ptr[n] = p; head[n] = p;
    }
}

__global__ void k_slot(const int* __restrict__ ei, int* __restrict__ head,
                       int* __restrict__ slot)
{
    int e = blockIdx.x * 256 + threadIdx.x;
    if (e < NE) slot[e] = atomicAdd(&head[ei[e]], 1);
}

// ---------------- single MFMA GEMM pass: h (bf16, CSR-slotted) + column stats ----
// 64 edges x 128 cols per block; wave w owns m-tiles {w, w+4}.
// LDS rows stride 200 u16 (bank stride 100 dw == 4 mod 8 -> free 2-way aliasing).
template <int EAB>
__global__ __launch_bounds__(256) void k_gemm_h(
    const u16* __restrict__ afb, const float* __restrict__ ea,
    const u16* __restrict__ eab, const int* __restrict__ ei,
    const int* __restrict__ slot, const u16* __restrict__ wT,
    u16* __restrict__ h, float* __restrict__ spread)
{
    __shared__ __align__(16) u16 sTl[64 * 200];
    __shared__ int sSrc[64], sDst[64], sSlot[64];
    const int tid = threadIdx.x;
    const int e0 = blockIdx.x * 64;

    if (tid < 64) sSrc[tid] = ei[e0 + tid];
    else if (tid < 128) sDst[tid - 64] = ei[NE + e0 + tid - 64];
    else if (tid < 192) sSlot[tid - 128] = slot[e0 + tid - 128];
    __syncthreads();

    // stage af[src] (k 0..63) and af[dst] (k 64..127): 16-byte chunks
    for (int i = tid; i < 1024; i += 256) {
        int e = i >> 4, q = i & 15;
        const u16* g = (q < 8) ? (afb + (long)sSrc[e] * 64 + q * 8)
                               : (afb + (long)sDst[e] * 64 + (q - 8) * 8);
        *(short8*)(sTl + e * 200 + q * 8) = *(const short8*)g;
    }
    if (EAB) {
        // bf16 edge_attr rows (48 cols) + zero pad cols 176..191
        for (int i = tid; i < 512; i += 256) {
            if (i < 384) {
                int e = i / 6, q = i - e * 6;
                *(short8*)(sTl + e * 200 + 128 + q * 8) =
                    *(const short8*)(eab + (long)(e0 + e) * 48 + q * 8);
            } else {
                int j = i - 384; int e = j >> 1, q = j & 1;
                short8 z = {0,0,0,0,0,0,0,0};
                *(short8*)(sTl + e * 200 + 176 + q * 8) = z;
            }
        }
    } else {
        for (int i = tid; i < 64 * 64; i += 256) {
            int e = i >> 6, c = i & 63;
            float v = (c < NBRD) ? ea[(long)(e0 + e) * NBRD + c] : 0.f;
            sTl[e * 200 + 128 + c] = f2b(v);
        }
    }
    __syncthreads();

    const int lane = tid & 63, w = tid >> 6;
    const int n16 = lane & 15, quad = lane >> 4;

    short8 A0[6], A1[6];
    {
        const u16* b0 = wT + (16 * w + n16) * 192 + quad * 8;
        const u16* b1 = wT + (16 * (w + 4) + n16) * 192 + quad * 8;
#pragma unroll
        for (int ks = 0; ks < 6; ks++) {
            A0[ks] = *(const short8*)(b0 + ks * 32);
            A1[ks] = *(const short8*)(b1 + ks * 32);
        }
    }

    const int j0 = 16 * w + 4 * quad;
    float s0[4] = {0,0,0,0}, q0[4] = {0,0,0,0}, s1[4] = {0,0,0,0}, q1[4] = {0,0,0,0};

    for (int t = 0; t < 4; t++) {
        const u16* row = sTl + (16 * t + n16) * 200 + quad * 8;
        f32x4 acc0 = {0.f, 0.f, 0.f, 0.f}, acc1 = {0.f, 0.f, 0.f, 0.f};
#pragma unroll
        for (int ks = 0; ks < 6; ks++) {
            short8 b = *(const short8*)(row + ks * 32);
            acc0 = __builtin_amdgcn_mfma_f32_16x16x32_bf16(A0[ks], b, acc0, 0, 0, 0);
            acc1 = __builtin_amdgcn_mfma_f32_16x16x32_bf16(A1[ks], b, acc1, 0, 0, 0);
        }
#pragma unroll
        for (int r = 0; r < 4; r++) {
            s0[r] += acc0[r]; q0[r] = fmaf(acc0[r], acc0[r], q0[r]);
            s1[r] += acc1[r]; q1[r] = fmaf(acc1[r], acc1[r], q1[r]);
        }
        // write h row at CSR slot: scatter pass reads contiguously per node
        u16* hp = h + (long)sSlot[16 * t + n16] * 128 + j0;
        ushort4 v0 = make_ushort4(f2b(acc0[0]), f2b(acc0[1]), f2b(acc0[2]), f2b(acc0[3]));
        ushort4 v1 = make_ushort4(f2b(acc1[0]), f2b(acc1[1]), f2b(acc1[2]), f2b(acc1[3]));
        *(ushort4*)hp = v0;
        *(ushort4*)(hp + 64) = v1;
    }

#pragma unroll
    for (int m = 1; m < 16; m <<= 1) {
#pragma unroll
        for (int r = 0; r < 4; r++) {
            s0[r] += __shfl_xor(s0[r], m); q0[r] += __shfl_xor(q0[r], m);
            s1[r] += __shfl_xor(s1[r], m); q1[r] += __shfl_xor(q1[r], m);
        }
    }
    if (n16 == 0) {
        float* sp = spread + (blockIdx.x & (NSPREAD - 1)) * 256;
#pragma unroll
        for (int r = 0; r < 4; r++) {
            atomicAdd(sp + j0 + r,       s0[r]);
            atomicAdd(sp + 128 + j0 + r, q0[r]);
            atomicAdd(sp + 64 + j0 + r,  s1[r]);
            atomicAdd(sp + 192 + j0 + r, q1[r]);
        }
    }
}

// ---------------- fallback two-pass GEMM (tier1, tiny ws) ----------------------
template <int MODE>
__global__ __launch_bounds__(256) void k_gemm(
    const u16* __restrict__ afb, const float* __restrict__ ea,
    const int* __restrict__ ei, const u16* __restrict__ wT,
    const float* __restrict__ sc, float* __restrict__ outbuf)
{
    __shared__ __align__(16) u16 sTl[64 * 200];
    __shared__ int sSrc[64], sDst[64];
    const int tid = threadIdx.x;
    const int e0 = blockIdx.x * 64;

    if (tid < 64) sSrc[tid] = ei[e0 + tid];
    else if (tid < 128) sDst[tid - 64] = ei[NE + e0 + tid - 64];
    __syncthreads();
    for (int i = tid; i < 1024; i += 256) {
        int e = i >> 4, q = i & 15;
        const u16* g = (q < 8) ? (afb + (long)sSrc[e] * 64 + q * 8)
                               : (afb + (long)sDst[e] * 64 + (q - 8) * 8);
        *(short8*)(sTl + e * 200 + q * 8) = *(const short8*)g;
    }
    for (int i = tid; i < 64 * 64; i += 256) {
        int e = i >> 6, c = i & 63;
        float v = (c < NBRD) ? ea[(long)(e0 + e) * NBRD + c] : 0.f;
        sTl[e * 200 + 128 + c] = f2b(v);
    }
    __syncthreads();

    const int lane = tid & 63, w = tid >> 6;
    const int n16 = lane & 15, quad = lane >> 4;
    short8 A0[6], A1[6];
    {
        const u16* b0 = wT + (16 * w + n16) * 192 + quad * 8;
        const u16* b1 = wT + (16 * (w + 4) + n16) * 192 + quad * 8;
#pragma unroll
        for (int ks = 0; ks < 6; ks++) {
            A0[ks] = *(const short8*)(b0 + ks * 32);
            A1[ks] = *(const short8*)(b1 + ks * 32);
        }
    }
    const int j0 = 16 * w + 4 * quad;
    float s0[4] = {0,0,0,0}, q0[4] = {0,0,0,0}, s1[4] = {0,0,0,0}, q1[4] = {0,0,0,0};
    float scf[4], shf[4], scc[4], shc[4];
    if (MODE == 1) {
#pragma unroll
        for (int r = 0; r < 4; r++) {
            scf[r] = sc[j0 + r];        shf[r] = sc[128 + j0 + r];
            scc[r] = sc[64 + j0 + r];   shc[r] = sc[192 + j0 + r];
        }
    }
    for (int t = 0; t < 4; t++) {
        const u16* row = sTl + (16 * t + n16) * 200 + quad * 8;
        f32x4 acc0 = {0.f, 0.f, 0.f, 0.f}, acc1 = {0.f, 0.f, 0.f, 0.f};
#pragma unroll
        for (int ks = 0; ks < 6; ks++) {
            short8 b = *(const short8*)(row + ks * 32);
            acc0 = __builtin_amdgcn_mfma_f32_16x16x32_bf16(A0[ks], b, acc0, 0, 0, 0);
            acc1 = __builtin_amdgcn_mfma_f32_16x16x32_bf16(A1[ks], b, acc1, 0, 0, 0);
        }
        if (MODE == 0) {
#pragma unroll
            for (int r = 0; r < 4; r++) {
                s0[r] += acc0[r]; q0[r] = fmaf(acc0[r], acc0[r], q0[r]);
                s1[r] += acc1[r]; q1[r] = fmaf(acc1[r], acc1[r], q1[r]);
            }
        } else {
            int src = sSrc[16 * t + n16];
            float* dst = outbuf + (long)src * 64 + j0;
#pragma unroll
            for (int r = 0; r < 4; r++) {
                float f  = fmaf(acc0[r], scf[r], shf[r]);
                float cc = fmaf(acc1[r], scc[r], shc[r]);
                float sig = 1.f / (1.f + expf(-f));
                float sp  = fmaxf(cc, 0.f) + log1pf(expf(-fabsf(cc)));
                atomicAdd(dst + r, sig * sp);
            }
        }
    }
    if (MODE == 0) {
#pragma unroll
        for (int m = 1; m < 16; m <<= 1) {
#pragma unroll
            for (int r = 0; r < 4; r++) {
                s0[r] += __shfl_xor(s0[r], m); q0[r] += __shfl_xor(q0[r], m);
                s1[r] += __shfl_xor(s1[r], m); q1[r] += __shfl_xor(q1[r], m);
            }
        }
        if (n16 == 0) {
            float* sp = outbuf + (blockIdx.x & (NSPREAD - 1)) * 256;
#pragma unroll
            for (int r = 0; r < 4; r++) {
                atomicAdd(sp + j0 + r,       s0[r]);
                atomicAdd(sp + 128 + j0 + r, q0[r]);
                atomicAdd(sp + 64 + j0 + r,  s1[r]);
                atomicAdd(sp + 192 + j0 + r, q1[r]);
            }
        }
    }
}

// ---------------- bn1 finalize (fc_b folds out) ----------------
__global__ void k_bn1fin(const float* __restrict__ spread,
                         const float* __restrict__ g, const float* __restrict__ b,
                         float* __restrict__ sc)
{
    int c = threadIdx.x;  // 128
    float s = 0.f, q = 0.f;
    for (int k = 0; k < NSPREAD; k++) { s += spread[k * 256 + c]; q += spread[k * 256 + 128 + c]; }
    float mean_acc = s / (float)NE;
    float var = q / (float)NE - mean_acc * mean_acc;
    float scale = g[c] * rsqrtf(var + 1e-5f);
    sc[c] = scale;
    sc[128 + c] = b[c] - mean_acc * scale;
}

// ---------------- CSR gather: BN1 + gate + per-node sum, vectorized ------------
// One wave per node. lane = (es=edge-sub 0..7, cg=chan-group 0..7); per iteration
// the wave reads 8 contiguous h rows (2 KB coalesced) via short8 loads.
__global__ __launch_bounds__(256) void k_scatter(
    const u16* __restrict__ h, const int* __restrict__ ptr,
    const int* __restrict__ cnt, const float* __restrict__ sc,
    float* __restrict__ summed)
{
    int tid = threadIdx.x;
    int n = blockIdx.x * 4 + (tid >> 6);
    int l = tid & 63;
    int es = l & 7, cg = l >> 3;

    float4 a0 = *(const float4*)(sc + cg * 8);
    float4 a1 = *(const float4*)(sc + cg * 8 + 4);
    float4 b0 = *(const float4*)(sc + 128 + cg * 8);
    float4 b1 = *(const float4*)(sc + 128 + cg * 8 + 4);
    float4 c0 = *(const float4*)(sc + 64 + cg * 8);
    float4 c1 = *(const float4*)(sc + 64 + cg * 8 + 4);
    float4 d0 = *(const float4*)(sc + 192 + cg * 8);
    float4 d1 = *(const float4*)(sc + 192 + cg * 8 + 4);
    float scf[8] = {a0.x,a0.y,a0.z,a0.w,a1.x,a1.y,a1.z,a1.w};
    float shf[8] = {b0.x,b0.y,b0.z,b0.w,b1.x,b1.y,b1.z,b1.w};
    float scc[8] = {c0.x,c0.y,c0.z,c0.w,c1.x,c1.y,c1.z,c1.w};
    float shc[8] = {d0.x,d0.y,d0.z,d0.w,d1.x,d1.y,d1.z,d1.w};

    int p0 = ptr[n], deg = cnt[n];
    float acc[8] = {0,0,0,0,0,0,0,0};
    for (int i = 0; i < deg; i += 8) {
        int idx = i + es;
        bool valid = idx < deg;
        long r = p0 + (valid ? idx : 0);
        const u16* hr = h + r * 128;
        short8 f8 = *(const short8*)(hr + cg * 8);
        short8 c8 = *(const short8*)(hr + 64 + cg * 8);
#pragma unroll
        for (int j = 0; j < 8; j++) {
            float f  = fmaf(b2f((u16)f8[j]), scf[j], shf[j]);
            float cc = fmaf(b2f((u16)c8[j]), scc[j], shc[j]);
            float sig = 1.f / (1.f + expf(-f));
            float sp  = fmaxf(cc, 0.f) + log1pf(expf(-fabsf(cc)));
            acc[j] += valid ? sig * sp : 0.f;
        }
    }
#pragma unroll
    for (int m = 1; m < 8; m <<= 1)
#pragma unroll
        for (int j = 0; j < 8; j++) acc[j] += __shfl_xor(acc[j], m);
    if (es == 0) {
        float* sp = summed + (long)n * 64 + cg * 8;
        float4 v0 = {acc[0], acc[1], acc[2], acc[3]};
        float4 v1 = {acc[4], acc[5], acc[6], acc[7]};
        *(float4*)sp = v0;
        *(float4*)(sp + 4) = v1;
    }
}

// ---------------- bn2 stats ----------------
__global__ __launch_bounds__(256) void k_bn2stats(const float* __restrict__ summed,
                                                  float* __restrict__ acc2)
{
    int tid = threadIdx.x; int c = tid & 63; int sub = tid >> 6;
    float s = 0.f, q = 0.f;
    for (int r = blockIdx.x * 4 + sub; r < NN; r += 4 * 128) {
        float v = summed[(long)r * 64 + c]; s += v; q = fmaf(v, v, q);
    }
    __shared__ float rs[256], rq[256];
    rs[tid] = s; rq[tid] = q; __syncthreads();
    if (tid < 64) {
        s = rs[tid] + rs[tid + 64] + rs[tid + 128] + rs[tid + 192];
        q = rq[tid] + rq[tid + 64] + rq[tid + 128] + rq[tid + 192];
        atomicAdd(&acc2[tid], s);
        atomicAdd(&acc2[64 + tid], q);
    }
}

// bn2 coefs + init the 256 crys_fea outputs to out_b
__global__ void k_bn2fin(const float* __restrict__ acc2,
                         const float* __restrict__ g, const float* __restrict__ b,
                         float* __restrict__ sc2, const float* __restrict__ outb,
                         float* __restrict__ out)
{
    int c = threadIdx.x;  // 256
    if (c < 64) {
        float mean = acc2[c] / (float)NN;
        float var = acc2[64 + c] / (float)NN - mean * mean;
        float scale = g[c] * rsqrtf(var + 1e-5f);
        sc2[c] = scale;
        sc2[64 + c] = b[c] - mean * scale;
    }
    out[(long)NN * 64 + c] = outb[0];
}

// ---------------- atom_out + silu + logits + segment max ----------------
__global__ __launch_bounds__(256) void k_nodepost(
    const float* __restrict__ summed, const float* __restrict__ sc2,
    const float* __restrict__ attW, const float* __restrict__ attb,
    const int* __restrict__ batch, float* __restrict__ out,
    float* __restrict__ elog, unsigned* __restrict__ segmax)
{
    int tid = threadIdx.x; int n = blockIdx.x * 4 + (tid >> 6); int c = tid & 63;
    float v = summed[(long)n * 64 + c];
    float ao = fmaf(v, sc2[c], sc2[64 + c]);
    out[(long)n * 64 + c] = ao;
    float h = ao / (1.f + expf(-ao));
    float p = h * attW[c];
#pragma unroll
    for (int off = 32; off; off >>= 1) p += __shfl_down(p, off, 64);
    if (c == 0) {
        float logit = p + attb[0];
        elog[n] = logit;
        unsigned u = __float_as_uint(logit);
        u = (u & 0x80000000u) ? ~u : (u | 0x80000000u);
        atomicMax(&segmax[batch[n]], u);
    }
}

__global__ void k_denom(const int* __restrict__ batch,
                        const unsigned* __restrict__ segmax,
                        float* __restrict__ elog, float* __restrict__ denom)
{
    int n = blockIdx.x * 256 + threadIdx.x;
    if (n >= NN) return;
    int b = batch[n];
    unsigned u = segmax[b];
    u = (u & 0x80000000u) ? (u & 0x7FFFFFFFu) : ~u;
    float e = expf(elog[n] - __uint_as_float(u));
    elog[n] = e;
    atomicAdd(&denom[b], e);
}

// weighted pooling fused with out_W projection: crys_fea[b] = sum alpha*(h . outW)
__global__ __launch_bounds__(256) void k_crys(
    const float* __restrict__ atom_out, const float* __restrict__ elog,
    const float* __restrict__ denom, const int* __restrict__ batch,
    const float* __restrict__ outW, float* __restrict__ out)
{
    int tid = threadIdx.x; int n = blockIdx.x * 4 + (tid >> 6); int l = tid & 63;
    int b = batch[n];
    float alpha = elog[n] / denom[b];
    float ao = atom_out[(long)n * 64 + l];
    float h = ao / (1.f + expf(-ao));
    float p = h * outW[l];
#pragma unroll
    for (int off = 32; off; off >>= 1) p += __shfl_down(p, off, 64);
    if (l == 0) atomicAdd(&out[(long)NN * 64 + b], alpha * p);
}

extern "C" void kernel_launch(void* const* d_in, const int* in_sizes, int n_in,
                              void* d_out, int out_size, void* d_ws, size_t ws_size,
                              hipStream_t stream)
{
    const float* x    = (const float*)d_in[0];
    const float* eatt = (const float*)d_in[1];
    const float* lf   = (const float*)d_in[2];
    const int*   ei   = (const int*)d_in[3];
    const int*   batch= (const int*)d_in[4];
    const float* embW = (const float*)d_in[5];
    const float* embB = (const float*)d_in[6];
    const float* fcW  = (const float*)d_in[7];
    // d_in[8] fc_b folds into bn1 shift
    const float* bn1g = (const float*)d_in[9];
    const float* bn1b = (const float*)d_in[10];
    const float* bn2g = (const float*)d_in[11];
    const float* bn2b = (const float*)d_in[12];
    const float* attW = (const float*)d_in[13];
    const float* attB = (const float*)d_in[14];
    const float* outW = (const float*)d_in[15];
    const float* outB = (const float*)d_in[16];
    float* out = (float*)d_out;
    float* ws  = (float*)d_ws;

    u16* afb  = (u16*)(ws + OFF_AFB);
    u16* wT   = (u16*)(ws + OFF_WT);
    int* cnt  = (int*)(ws + OFF_CNT);
    int* ptr  = (int*)(ws + OFF_PTR);
    int* head = (int*)(ws + OFF_HEAD);
    int* bsum = (int*)(ws + OFF_BSUM);
    int* bofs = (int*)(ws + OFF_BOFS);
    int* slot = (int*)(ws + OFF_SLOT);
    u16* h    = (u16*)(ws + OFF_H);
    u16* eab  = (u16*)(ws + OFF_EAB);

    const bool t3 = ws_size >= (size_t)OFF_T3_END * sizeof(float);
    const bool t2 = ws_size >= (size_t)OFF_T2_END * sizeof(float);

    k_embed<<<12500, 256, 0, stream>>>(x, lf, embW, embB, afb);
    k_prepw<<<96, 256, 0, stream>>>(fcW, wT);

    if (t2) {
        // zero: bn1 spread/coefs, bn2, elog, segmax, denom, cnt
        hipMemsetAsync(ws + OFF_BN1SPR, 0,
                       (size_t)(OFF_PTR - OFF_BN1SPR) * sizeof(float), stream);
        if (t3) k_prepea<<<NE * 48 / 256, 256, 0, stream>>>(eatt, eab);
        // CSR over src
        k_hist<<<(NE + 255) / 256, 256, 0, stream>>>(ei, cnt);
        k_partial<<<(NN + SCAN_B - 1) / SCAN_B, SCAN_B, 0, stream>>>(cnt, ptr, bsum);
        k_scanb<<<1, 256, 0, stream>>>(bsum, bofs, (NN + SCAN_B - 1) / SCAN_B);
        k_addofs<<<(NN + 255) / 256, 256, 0, stream>>>(ptr, bofs, head);
        k_slot<<<(NE + 255) / 256, 256, 0, stream>>>(ei, head, slot);
        // single GEMM pass: slotted h + stats, then BN coefs, then gather
        if (t3)
            k_gemm_h<1><<<NE / 64, 256, 0, stream>>>(afb, eatt, eab, ei, slot, wT,
                                                     h, ws + OFF_BN1SPR);
        else
            k_gemm_h<0><<<NE / 64, 256, 0, stream>>>(afb, eatt, eab, ei, slot, wT,
                                                     h, ws + OFF_BN1SPR);
        k_bn1fin<<<1, 128, 0, stream>>>(ws + OFF_BN1SPR, bn1g, bn1b, ws + OFF_BN1SC);
        k_scatter<<<NN / 4, 256, 0, stream>>>(h, ptr, cnt, ws + OFF_BN1SC,
                                              ws + OFF_SUMMED);
    } else {
        // fallback: two-pass with atomic scatter
        hipMemsetAsync(ws + OFF_SUMMED, 0,
                       (size_t)(OFF_PTR - OFF_SUMMED) * sizeof(float), stream);
        k_gemm<0><<<NE / 64, 256, 0, stream>>>(afb, eatt, ei, wT, ws + OFF_BN1SC,
                                               ws + OFF_BN1SPR);
        k_bn1fin<<<1, 128, 0, stream>>>(ws + OFF_BN1SPR, bn1g, bn1b, ws + OFF_BN1SC);
        k_gemm<1><<<NE / 64, 256, 0, stream>>>(afb, eatt, ei, wT, ws + OFF_BN1SC,
                                               ws + OFF_SUMMED);
    }

    k_bn2stats<<<128, 256, 0, stream>>>(ws + OFF_SUMMED, ws + OFF_BN2ACC);
    k_bn2fin<<<1, 256, 0, stream>>>(ws + OFF_BN2ACC, bn2g, bn2b, ws + OFF_BN2SC,
                                    outB, out);
    k_nodepost<<<12500, 256, 0, stream>>>(ws + OFF_SUMMED, ws + OFF_BN2SC, attW, attB,
                                          batch, out, ws + OFF_ELOG,
                                          (unsigned*)(ws + OFF_SEGMAX));
    k_denom<<<196, 256, 0, stream>>>(batch, (const unsigned*)(ws + OFF_SEGMAX),
                                     ws + OFF_ELOG, ws + OFF_DENOM);
    k_crys<<<12500, 256, 0, stream>>>(out, ws + OFF_ELOG, ws + OFF_DENOM, batch,
                                      outW, out);
}

// Round 5
// 1204.867 us; speedup vs baseline: 1.1589x; 1.1589x over previous
//
#include <hip/hip_runtime.h>
#include <math.h>

#define NN 50000
#define NE 1000000
#define NG 256
#define ORIGD 92
#define NBRD 41
#define NSPREAD 32
#define SCAN_B 256

typedef unsigned short u16;
typedef __attribute__((ext_vector_type(8))) short short8;   // 8 x bf16 MFMA frag
typedef __attribute__((ext_vector_type(4))) float f32x4;    // MFMA accumulator

// ---- workspace layout (float offsets) ----
#define OFF_AFB     0                        // 50000*64 bf16
#define OFF_SUMMED  1600000                  // 50000*64 fp32
#define OFF_WT      4800000                  // 128*192 bf16
#define OFF_BN1SPR  4812288                  // 32*256
#define OFF_BN1SC   4820480                  // 256
#define OFF_BN2ACC  4820736                  // 128
#define OFF_BN2SC   4820864                  // 128
#define OFF_ELOG    4820992                  // 50000
#define OFF_SEGMAX  4870992                  // 256
#define OFF_DENOM   4871248                  // 256
#define OFF_CNT     4871504                  // 50000 int
#define OFF_PTR     4921504                  // 50000 int
#define OFF_HEAD    4971504                  // 50000 int
#define OFF_BSUM    5021504                  // 256 int
#define OFF_BOFS    5021760                  // 256 int
#define OFF_EIDX    5022016                  // 1M int (edge ids in CSR order)
#define OFF_H       6022016                  // 1M*128 bf16 (256 MB)
#define OFF_T2_END  70022016                 // ~280 MB total

__device__ __forceinline__ u16 f2b(float f) {          // fp32 -> bf16 RNE
    unsigned u = __float_as_uint(f);
    return (u16)((u + 0x7FFFu + ((u >> 16) & 1u)) >> 16);
}
__device__ __forceinline__ float b2f(u16 u) {
    return __uint_as_float(((unsigned)u) << 16);
}
// fast gate: sigmoid(f) * softplus(cc) via native v_exp/v_log/v_rcp (~1 ulp)
__device__ __forceinline__ float gate(float f, float cc) {
    float sig = __builtin_amdgcn_rcpf(1.f + __expf(-f));
    float sp  = fmaxf(cc, 0.f) + __logf(1.f + __expf(-fabsf(cc)));
    return sig * sp;
}
__device__ __forceinline__ float fsilu(float x) {
    return x * __builtin_amdgcn_rcpf(1.f + __expf(-x));
}

// ---------------- embed: afb = bf16(x@emb_W + emb_b + lower_f) ----------------
__global__ __launch_bounds__(256) void k_embed(
    const float* __restrict__ x, const float* __restrict__ lf,
    const float* __restrict__ W, const float* __restrict__ b,
    u16* __restrict__ afb)
{
    int gid = blockIdx.x * 256 + threadIdx.x;
    int n = gid >> 6, c = gid & 63;
    const float* xr = x + (long)n * ORIGD;
    float acc = b[c] + lf[gid];
#pragma unroll 4
    for (int k = 0; k < ORIGD; k++)
        acc = fmaf(xr[k], W[k * 64 + c], acc);
    afb[gid] = f2b(acc);
}

// ---------------- prep: wT[j][k] = bf16(fc_W[k][j]), K padded 169->192 ----------------
__global__ void k_prepw(const float* __restrict__ fcW, u16* __restrict__ wT)
{
    int i = blockIdx.x * 256 + threadIdx.x;        // 24576
    int j = i / 192, k = i - j * 192;
    wT[i] = (k < 169) ? f2b(fcW[k * 128 + j]) : (u16)0;
}

// ---------------- CSR build ----------------
__global__ void k_hist(const int* __restrict__ ei, int* __restrict__ cnt)
{
    int e = blockIdx.x * 256 + threadIdx.x;
    if (e < NE) atomicAdd(&cnt[ei[e]], 1);
}

__global__ void k_partial(const int* __restrict__ cnt, int* __restrict__ lofs,
                          int* __restrict__ bsum)
{
    __shared__ int sd[SCAN_B];
    int t = threadIdx.x, b = blockIdx.x, n = b * SCAN_B + t;
    int v = (n < NN) ? cnt[n] : 0;
    sd[t] = v; __syncthreads();
    for (int o = 1; o < SCAN_B; o <<= 1) {
        int x = (t >= o) ? sd[t - o] : 0;
        __syncthreads();
        sd[t] += x;
        __syncthreads();
    }
    if (n < NN) lofs[n] = sd[t] - v;
    if (t == SCAN_B - 1) bsum[b] = sd[t];
}

__global__ void k_scanb(const int* __restrict__ bsum, int* __restrict__ bofs, int nb)
{
    __shared__ int sd[256];
    int t = threadIdx.x;
    int v = (t < nb) ? bsum[t] : 0;
    sd[t] = v; __syncthreads();
    for (int o = 1; o < 256; o <<= 1) {
        int x = (t >= o) ? sd[t - o] : 0;
        __syncthreads();
        sd[t] += x;
        __syncthreads();
    }
    bofs[t] = sd[t] - v;
}

__global__ void k_addofs(int* __restrict__ ptr, const int* __restrict__ bofs,
                         int* __restrict__ head)
{
    int n = blockIdx.x * 256 + threadIdx.x;
    if (n < NN) {
        int p = ptr[n] + bofs[n >> 8];
        ptr[n] = p; head[n] = p;
    }
}

__global__ void k_fill(const int* __restrict__ ei, int* __restrict__ head,
                       int* __restrict__ eidx)
{
    int e = blockIdx.x * 256 + threadIdx.x;
    if (e < NE) {
        int pos = atomicAdd(&head[ei[e]], 1);
        eidx[pos] = e;
    }
}

// ---------------- single MFMA GEMM pass: h (bf16, contiguous by edge) + stats ----
// 64 edges x 128 cols per block; wave w owns m-tiles {w, w+4}.
// LDS rows stride 200 u16 (bank stride 100 dw == 4 mod 8 -> free 2-way aliasing).
__global__ __launch_bounds__(256) void k_gemm_h(
    const u16* __restrict__ afb, const float* __restrict__ ea,
    const int* __restrict__ ei, const u16* __restrict__ wT,
    u16* __restrict__ h, float* __restrict__ spread)
{
    __shared__ __align__(16) u16 sTl[64 * 200];
    __shared__ int sSrc[64], sDst[64];
    const int tid = threadIdx.x;
    const int e0 = blockIdx.x * 64;

    if (tid < 64) sSrc[tid] = ei[e0 + tid];
    else if (tid < 128) sDst[tid - 64] = ei[NE + e0 + tid - 64];
    __syncthreads();

    for (int i = tid; i < 1024; i += 256) {
        int e = i >> 4, q = i & 15;
        const u16* g = (q < 8) ? (afb + (long)sSrc[e] * 64 + q * 8)
                               : (afb + (long)sDst[e] * 64 + (q - 8) * 8);
        *(short8*)(sTl + e * 200 + q * 8) = *(const short8*)g;
    }
    for (int i = tid; i < 64 * 64; i += 256) {
        int e = i >> 6, c = i & 63;
        float v = (c < NBRD) ? ea[(long)(e0 + e) * NBRD + c] : 0.f;
        sTl[e * 200 + 128 + c] = f2b(v);
    }
    __syncthreads();

    const int lane = tid & 63, w = tid >> 6;
    const int n16 = lane & 15, quad = lane >> 4;

    short8 A0[6], A1[6];
    {
        const u16* b0 = wT + (16 * w + n16) * 192 + quad * 8;
        const u16* b1 = wT + (16 * (w + 4) + n16) * 192 + quad * 8;
#pragma unroll
        for (int ks = 0; ks < 6; ks++) {
            A0[ks] = *(const short8*)(b0 + ks * 32);
            A1[ks] = *(const short8*)(b1 + ks * 32);
        }
    }

    const int j0 = 16 * w + 4 * quad;
    float s0[4] = {0,0,0,0}, q0[4] = {0,0,0,0}, s1[4] = {0,0,0,0}, q1[4] = {0,0,0,0};

    for (int t = 0; t < 4; t++) {
        const u16* row = sTl + (16 * t + n16) * 200 + quad * 8;
        f32x4 acc0 = {0.f, 0.f, 0.f, 0.f}, acc1 = {0.f, 0.f, 0.f, 0.f};
#pragma unroll
        for (int ks = 0; ks < 6; ks++) {
            short8 b = *(const short8*)(row + ks * 32);
            acc0 = __builtin_amdgcn_mfma_f32_16x16x32_bf16(A0[ks], b, acc0, 0, 0, 0);
            acc1 = __builtin_amdgcn_mfma_f32_16x16x32_bf16(A1[ks], b, acc1, 0, 0, 0);
        }
#pragma unroll
        for (int r = 0; r < 4; r++) {
            s0[r] += acc0[r]; q0[r] = fmaf(acc0[r], acc0[r], q0[r]);
            s1[r] += acc1[r]; q1[r] = fmaf(acc1[r], acc1[r], q1[r]);
        }
        int ge = e0 + 16 * t + n16;
        u16* hp = h + (long)ge * 128 + j0;
        ushort4 v0 = make_ushort4(f2b(acc0[0]), f2b(acc0[1]), f2b(acc0[2]), f2b(acc0[3]));
        ushort4 v1 = make_ushort4(f2b(acc1[0]), f2b(acc1[1]), f2b(acc1[2]), f2b(acc1[3]));
        *(ushort4*)hp = v0;
        *(ushort4*)(hp + 64) = v1;
    }

#pragma unroll
    for (int m = 1; m < 16; m <<= 1) {
#pragma unroll
        for (int r = 0; r < 4; r++) {
            s0[r] += __shfl_xor(s0[r], m); q0[r] += __shfl_xor(q0[r], m);
            s1[r] += __shfl_xor(s1[r], m); q1[r] += __shfl_xor(q1[r], m);
        }
    }
    if (n16 == 0) {
        float* sp = spread + (blockIdx.x & (NSPREAD - 1)) * 256;
#pragma unroll
        for (int r = 0; r < 4; r++) {
            atomicAdd(sp + j0 + r,       s0[r]);
            atomicAdd(sp + 128 + j0 + r, q0[r]);
            atomicAdd(sp + 64 + j0 + r,  s1[r]);
            atomicAdd(sp + 192 + j0 + r, q1[r]);
        }
    }
}

// ---------------- fallback two-pass GEMM (tiny ws) ----------------------------
template <int MODE>
__global__ __launch_bounds__(256) void k_gemm(
    const u16* __restrict__ afb, const float* __restrict__ ea,
    const int* __restrict__ ei, const u16* __restrict__ wT,
    const float* __restrict__ sc, float* __restrict__ outbuf)
{
    __shared__ __align__(16) u16 sTl[64 * 200];
    __shared__ int sSrc[64], sDst[64];
    const int tid = threadIdx.x;
    const int e0 = blockIdx.x * 64;

    if (tid < 64) sSrc[tid] = ei[e0 + tid];
    else if (tid < 128) sDst[tid - 64] = ei[NE + e0 + tid - 64];
    __syncthreads();
    for (int i = tid; i < 1024; i += 256) {
        int e = i >> 4, q = i & 15;
        const u16* g = (q < 8) ? (afb + (long)sSrc[e] * 64 + q * 8)
                               : (afb + (long)sDst[e] * 64 + (q - 8) * 8);
        *(short8*)(sTl + e * 200 + q * 8) = *(const short8*)g;
    }
    for (int i = tid; i < 64 * 64; i += 256) {
        int e = i >> 6, c = i & 63;
        float v = (c < NBRD) ? ea[(long)(e0 + e) * NBRD + c] : 0.f;
        sTl[e * 200 + 128 + c] = f2b(v);
    }
    __syncthreads();

    const int lane = tid & 63, w = tid >> 6;
    const int n16 = lane & 15, quad = lane >> 4;
    short8 A0[6], A1[6];
    {
        const u16* b0 = wT + (16 * w + n16) * 192 + quad * 8;
        const u16* b1 = wT + (16 * (w + 4) + n16) * 192 + quad * 8;
#pragma unroll
        for (int ks = 0; ks < 6; ks++) {
            A0[ks] = *(const short8*)(b0 + ks * 32);
            A1[ks] = *(const short8*)(b1 + ks * 32);
        }
    }
    const int j0 = 16 * w + 4 * quad;
    float s0[4] = {0,0,0,0}, q0[4] = {0,0,0,0}, s1[4] = {0,0,0,0}, q1[4] = {0,0,0,0};
    float scf[4], shf[4], scc[4], shc[4];
    if (MODE == 1) {
#pragma unroll
        for (int r = 0; r < 4; r++) {
            scf[r] = sc[j0 + r];        shf[r] = sc[128 + j0 + r];
            scc[r] = sc[64 + j0 + r];   shc[r] = sc[192 + j0 + r];
        }
    }
    for (int t = 0; t < 4; t++) {
        const u16* row = sTl + (16 * t + n16) * 200 + quad * 8;
        f32x4 acc0 = {0.f, 0.f, 0.f, 0.f}, acc1 = {0.f, 0.f, 0.f, 0.f};
#pragma unroll
        for (int ks = 0; ks < 6; ks++) {
            short8 b = *(const short8*)(row + ks * 32);
            acc0 = __builtin_amdgcn_mfma_f32_16x16x32_bf16(A0[ks], b, acc0, 0, 0, 0);
            acc1 = __builtin_amdgcn_mfma_f32_16x16x32_bf16(A1[ks], b, acc1, 0, 0, 0);
        }
        if (MODE == 0) {
#pragma unroll
            for (int r = 0; r < 4; r++) {
                s0[r] += acc0[r]; q0[r] = fmaf(acc0[r], acc0[r], q0[r]);
                s1[r] += acc1[r]; q1[r] = fmaf(acc1[r], acc1[r], q1[r]);
            }
        } else {
            int src = sSrc[16 * t + n16];
            float* dst = outbuf + (long)src * 64 + j0;
#pragma unroll
            for (int r = 0; r < 4; r++) {
                float f  = fmaf(acc0[r], scf[r], shf[r]);
                float cc = fmaf(acc1[r], scc[r], shc[r]);
                atomicAdd(dst + r, gate(f, cc));
            }
        }
    }
    if (MODE == 0) {
#pragma unroll
        for (int m = 1; m < 16; m <<= 1) {
#pragma unroll
            for (int r = 0; r < 4; r++) {
                s0[r] += __shfl_xor(s0[r], m); q0[r] += __shfl_xor(q0[r], m);
                s1[r] += __shfl_xor(s1[r], m); q1[r] += __shfl_xor(q1[r], m);
            }
        }
        if (n16 == 0) {
            float* sp = outbuf + (blockIdx.x & (NSPREAD - 1)) * 256;
#pragma unroll
            for (int r = 0; r < 4; r++) {
                atomicAdd(sp + j0 + r,       s0[r]);
                atomicAdd(sp + 128 + j0 + r, q0[r]);
                atomicAdd(sp + 64 + j0 + r,  s1[r]);
                atomicAdd(sp + 192 + j0 + r, q1[r]);
            }
        }
    }
}

// ---------------- bn1 finalize (fc_b folds out) ----------------
__global__ void k_bn1fin(const float* __restrict__ spread,
                         const float* __restrict__ g, const float* __restrict__ b,
                         float* __restrict__ sc)
{
    int c = threadIdx.x;  // 128
    float s = 0.f, q = 0.f;
    for (int k = 0; k < NSPREAD; k++) { s += spread[k * 256 + c]; q += spread[k * 256 + 128 + c]; }
    float mean_acc = s / (float)NE;
    float var = q / (float)NE - mean_acc * mean_acc;
    float scale = g[c] * rsqrtf(var + 1e-5f);
    sc[c] = scale;
    sc[128 + c] = b[c] - mean_acc * scale;
}

// ---------------- CSR gather: BN1 + fast gate + per-node sum -------------------
// One wave per node. lane = (es=edge-sub 0..7, cg=chan-group 0..7); per iteration
// the wave reads 8 CSR-indexed h rows (8 x 256B) via short8 loads.
__global__ __launch_bounds__(256) void k_scatter(
    const u16* __restrict__ h, const int* __restrict__ ptr,
    const int* __restrict__ cnt, const int* __restrict__ eidx,
    const float* __restrict__ sc, float* __restrict__ summed)
{
    int tid = threadIdx.x;
    int n = blockIdx.x * 4 + (tid >> 6);
    int l = tid & 63;
    int es = l & 7, cg = l >> 3;

    float4 a0 = *(const float4*)(sc + cg * 8);
    float4 a1 = *(const float4*)(sc + cg * 8 + 4);
    float4 b0 = *(const float4*)(sc + 128 + cg * 8);
    float4 b1 = *(const float4*)(sc + 128 + cg * 8 + 4);
    float4 c0 = *(const float4*)(sc + 64 + cg * 8);
    float4 c1 = *(const float4*)(sc + 64 + cg * 8 + 4);
    float4 d0 = *(const float4*)(sc + 192 + cg * 8);
    float4 d1 = *(const float4*)(sc + 192 + cg * 8 + 4);
    float scf[8] = {a0.x,a0.y,a0.z,a0.w,a1.x,a1.y,a1.z,a1.w};
    float shf[8] = {b0.x,b0.y,b0.z,b0.w,b1.x,b1.y,b1.z,b1.w};
    float scc[8] = {c0.x,c0.y,c0.z,c0.w,c1.x,c1.y,c1.z,c1.w};
    float shc[8] = {d0.x,d0.y,d0.z,d0.w,d1.x,d1.y,d1.z,d1.w};

    int p0 = ptr[n], deg = cnt[n];
    float acc[8] = {0,0,0,0,0,0,0,0};
    for (int i = 0; i < deg; i += 8) {
        int idx = i + es;
        bool valid = idx < deg;
        int e = eidx[p0 + (valid ? idx : 0)];
        const u16* hr = h + (long)e * 128;
        short8 f8 = *(const short8*)(hr + cg * 8);
        short8 c8 = *(const short8*)(hr + 64 + cg * 8);
#pragma unroll
        for (int j = 0; j < 8; j++) {
            float f  = fmaf(b2f((u16)f8[j]), scf[j], shf[j]);
            float cc = fmaf(b2f((u16)c8[j]), scc[j], shc[j]);
            float g  = gate(f, cc);
            acc[j] += valid ? g : 0.f;
        }
    }
#pragma unroll
    for (int m = 1; m < 8; m <<= 1)
#pragma unroll
        for (int j = 0; j < 8; j++) acc[j] += __shfl_xor(acc[j], m);
    if (es == 0) {
        float* sp = summed + (long)n * 64 + cg * 8;
        float4 v0 = {acc[0], acc[1], acc[2], acc[3]};
        float4 v1 = {acc[4], acc[5], acc[6], acc[7]};
        *(float4*)sp = v0;
        *(float4*)(sp + 4) = v1;
    }
}

// ---------------- bn2 stats ----------------
__global__ __launch_bounds__(256) void k_bn2stats(const float* __restrict__ summed,
                                                  float* __restrict__ acc2)
{
    int tid = threadIdx.x; int c = tid & 63; int sub = tid >> 6;
    float s = 0.f, q = 0.f;
    for (int r = blockIdx.x * 4 + sub; r < NN; r += 4 * 128) {
        float v = summed[(long)r * 64 + c]; s += v; q = fmaf(v, v, q);
    }
    __shared__ float rs[256], rq[256];
    rs[tid] = s; rq[tid] = q; __syncthreads();
    if (tid < 64) {
        s = rs[tid] + rs[tid + 64] + rs[tid + 128] + rs[tid + 192];
        q = rq[tid] + rq[tid + 64] + rq[tid + 128] + rq[tid + 192];
        atomicAdd(&acc2[tid], s);
        atomicAdd(&acc2[64 + tid], q);
    }
}

// bn2 coefs + init the 256 crys_fea outputs to out_b
__global__ void k_bn2fin(const float* __restrict__ acc2,
                         const float* __restrict__ g, const float* __restrict__ b,
                         float* __restrict__ sc2, const float* __restrict__ outb,
                         float* __restrict__ out)
{
    int c = threadIdx.x;  // 256
    if (c < 64) {
        float mean = acc2[c] / (float)NN;
        float var = acc2[64 + c] / (float)NN - mean * mean;
        float scale = g[c] * rsqrtf(var + 1e-5f);
        sc2[c] = scale;
        sc2[64 + c] = b[c] - mean * scale;
    }
    out[(long)NN * 64 + c] = outb[0];
}

// ---------------- atom_out + silu + logits + segment max ----------------
__global__ __launch_bounds__(256) void k_nodepost(
    const float* __restrict__ summed, const float* __restrict__ sc2,
    const float* __restrict__ attW, const float* __restrict__ attb,
    const int* __restrict__ batch, float* __restrict__ out,
    float* __restrict__ elog, unsigned* __restrict__ segmax)
{
    int tid = threadIdx.x; int n = blockIdx.x * 4 + (tid >> 6); int c = tid & 63;
    float v = summed[(long)n * 64 + c];
    float ao = fmaf(v, sc2[c], sc2[64 + c]);
    out[(long)n * 64 + c] = ao;
    float h = fsilu(ao);
    float p = h * attW[c];
#pragma unroll
    for (int off = 32; off; off >>= 1) p += __shfl_down(p, off, 64);
    if (c == 0) {
        float logit = p + attb[0];
        elog[n] = logit;
        unsigned u = __float_as_uint(logit);
        u = (u & 0x80000000u) ? ~u : (u | 0x80000000u);
        atomicMax(&segmax[batch[n]], u);
    }
}

__global__ void k_denom(const int* __restrict__ batch,
                        const unsigned* __restrict__ segmax,
                        float* __restrict__ elog, float* __restrict__ denom)
{
    int n = blockIdx.x * 256 + threadIdx.x;
    if (n >= NN) return;
    int b = batch[n];
    unsigned u = segmax[b];
    u = (u & 0x80000000u) ? (u & 0x7FFFFFFFu) : ~u;
    float e = __expf(elog[n] - __uint_as_float(u));
    elog[n] = e;
    atomicAdd(&denom[b], e);
}

// weighted pooling fused with out_W projection: crys_fea[b] = sum alpha*(h . outW)
__global__ __launch_bounds__(256) void k_crys(
    const float* __restrict__ atom_out, const float* __restrict__ elog,
    const float* __restrict__ denom, const int* __restrict__ batch,
    const float* __restrict__ outW, float* __restrict__ out)
{
    int tid = threadIdx.x; int n = blockIdx.x * 4 + (tid >> 6); int l = tid & 63;
    int b = batch[n];
    float alpha = elog[n] / denom[b];
    float ao = atom_out[(long)n * 64 + l];
    float p = fsilu(ao) * outW[l];
#pragma unroll
    for (int off = 32; off; off >>= 1) p += __shfl_down(p, off, 64);
    if (l == 0) atomicAdd(&out[(long)NN * 64 + b], alpha * p);
}

extern "C" void kernel_launch(void* const* d_in, const int* in_sizes, int n_in,
                              void* d_out, int out_size, void* d_ws, size_t ws_size,
                              hipStream_t stream)
{
    const float* x    = (const float*)d_in[0];
    const float* eatt = (const float*)d_in[1];
    const float* lf   = (const float*)d_in[2];
    const int*   ei   = (const int*)d_in[3];
    const int*   batch= (const int*)d_in[4];
    const float* embW = (const float*)d_in[5];
    const float* embB = (const float*)d_in[6];
    const float* fcW  = (const float*)d_in[7];
    // d_in[8] fc_b folds into bn1 shift
    const float* bn1g = (const float*)d_in[9];
    const float* bn1b = (const float*)d_in[10];
    const float* bn2g = (const float*)d_in[11];
    const float* bn2b = (const float*)d_in[12];
    const float* attW = (const float*)d_in[13];
    const float* attB = (const float*)d_in[14];
    const float* outW = (const float*)d_in[15];
    const float* outB = (const float*)d_in[16];
    float* out = (float*)d_out;
    float* ws  = (float*)d_ws;

    u16* afb  = (u16*)(ws + OFF_AFB);
    u16* wT   = (u16*)(ws + OFF_WT);
    int* cnt  = (int*)(ws + OFF_CNT);
    int* ptr  = (int*)(ws + OFF_PTR);
    int* head = (int*)(ws + OFF_HEAD);
    int* bsum = (int*)(ws + OFF_BSUM);
    int* bofs = (int*)(ws + OFF_BOFS);
    int* eidx = (int*)(ws + OFF_EIDX);
    u16* h    = (u16*)(ws + OFF_H);

    const bool t2 = ws_size >= (size_t)OFF_T2_END * sizeof(float);

    k_embed<<<12500, 256, 0, stream>>>(x, lf, embW, embB, afb);
    k_prepw<<<96, 256, 0, stream>>>(fcW, wT);

    if (t2) {
        // zero: bn1 spread/coefs, bn2, elog, segmax, denom, cnt
        hipMemsetAsync(ws + OFF_BN1SPR, 0,
                       (size_t)(OFF_PTR - OFF_BN1SPR) * sizeof(float), stream);
        k_hist<<<(NE + 255) / 256, 256, 0, stream>>>(ei, cnt);
        k_partial<<<(NN + SCAN_B - 1) / SCAN_B, SCAN_B, 0, stream>>>(cnt, ptr, bsum);
        k_scanb<<<1, 256, 0, stream>>>(bsum, bofs, (NN + SCAN_B - 1) / SCAN_B);
        k_addofs<<<(NN + 255) / 256, 256, 0, stream>>>(ptr, bofs, head);
        k_fill<<<(NE + 255) / 256, 256, 0, stream>>>(ei, head, eidx);
        k_gemm_h<<<NE / 64, 256, 0, stream>>>(afb, eatt, ei, wT, h, ws + OFF_BN1SPR);
        k_bn1fin<<<1, 128, 0, stream>>>(ws + OFF_BN1SPR, bn1g, bn1b, ws + OFF_BN1SC);
        k_scatter<<<NN / 4, 256, 0, stream>>>(h, ptr, cnt, eidx, ws + OFF_BN1SC,
                                              ws + OFF_SUMMED);
    } else {
        hipMemsetAsync(ws + OFF_SUMMED, 0,
                       (size_t)(OFF_PTR - OFF_SUMMED) * sizeof(float), stream);
        k_gemm<0><<<NE / 64, 256, 0, stream>>>(afb, eatt, ei, wT, ws + OFF_BN1SC,
                                               ws + OFF_BN1SPR);
        k_bn1fin<<<1, 128, 0, stream>>>(ws + OFF_BN1SPR, bn1g, bn1b, ws + OFF_BN1SC);
        k_gemm<1><<<NE / 64, 256, 0, stream>>>(afb, eatt, ei, wT, ws + OFF_BN1SC,
                                               ws + OFF_SUMMED);
    }

    k_bn2stats<<<128, 256, 0, stream>>>(ws + OFF_SUMMED, ws + OFF_BN2ACC);
    k_bn2fin<<<1, 256, 0, stream>>>(ws + OFF_BN2ACC, bn2g, bn2b, ws + OFF_BN2SC,
                                    outB, out);
    k_nodepost<<<12500, 256, 0, stream>>>(ws + OFF_SUMMED, ws + OFF_BN2SC, attW, attB,
                                          batch, out, ws + OFF_ELOG,
                                          (unsigned*)(ws + OFF_SEGMAX));
    k_denom<<<196, 256, 0, stream>>>(batch, (const unsigned*)(ws + OFF_SEGMAX),
                                     ws + OFF_ELOG, ws + OFF_DENOM);
    k_crys<<<12500, 256, 0, stream>>>(out, ws + OFF_ELOG, ws + OFF_DENOM, batch,
                                      outW, out);
}